// Round 6
// baseline (479.914 us; speedup 1.0000x reference)
//
#include <hip/hip_runtime.h>
#include <math.h>

#define PSTR 72     // LDS fp16 patch row stride: 144 B (16B-aligned; 2-way bank aliasing = free)

typedef _Float16 half8 __attribute__((ext_vector_type(8)));
typedef float    f32x4 __attribute__((ext_vector_type(4)));

__device__ __forceinline__ float fast_tanh(float v) {
    float e = __expf(2.f * v);
    return 1.f - 2.f / (e + 1.f);
}
__device__ __forceinline__ float hsig(float v) {
    return fminf(fmaxf(0.2f * v + 0.5f, 0.f), 1.f);
}

// Pack weights: Wc[tap][n][ci]; ci<32 from Wx[tap][ci][n], ci>=32 from Wh[tap][ci-32][n]  (layout verified R2-R5)
__global__ void prep_w(const float* __restrict__ Wx, const float* __restrict__ Wh,
                       _Float16* __restrict__ Wc) {
    const int k = blockIdx.x;      // 0..575 = tap*64 + ci
    const int n = threadIdx.x;     // 0..127
    const int tap = k >> 6, ci = k & 63;
    const float v = (ci < 32) ? Wx[(tap * 32 + ci) * 128 + n]
                              : Wh[(tap * 32 + (ci - 32)) * 128 + n];
    Wc[(tap * 128 + n) * 64 + ci] = (_Float16)v;
}

// Fused timestep: conv(x_t,Wx)+conv(h,Wh)+bias -> gates -> LSTM -> BN -> out.
// Grid (8,8,8)=512 blocks (2/CU), 256 thr (4 waves). Block: 8x8 px x 128 ch.
// Wave (chg=w&1, mtg=w>>1): 32 px x 64 ch; ch = nt*32 + chg*16 + l15 -> nt IS the
// gate index, f = chg*16+l15; every lane holds all 4 gates of its 8 (px,f) pairs.
// B-frags direct from L2 (147 KB weight set); no barriers in K-loop.
__global__ __launch_bounds__(256, 2)
void step(const float* __restrict__ x,        // [B,T,H,W,32] fp32
          const _Float16* __restrict__ Wc,    // [9][128][64] fp16
          const float* __restrict__ bias,     // [128]
          const float* __restrict__ gamma_, const float* __restrict__ beta_,
          const float* __restrict__ mmean, const float* __restrict__ mvar,
          const _Float16* __restrict__ hprev, _Float16* __restrict__ hnext,
          float* __restrict__ csw, float* __restrict__ out, int t)
{
    __shared__ _Float16 patch[100 * PSTR];   // 14.4 KB: 10x10 halo x (32 x-ch | 32 h-ch)

    const int tid  = threadIdx.x;
    const int lane = tid & 63;
    const int w    = tid >> 6;
    const int l15  = lane & 15, quad = lane >> 4;
    const int chg  = w & 1, mtg = w >> 1;
    const int tx = blockIdx.x, ty = blockIdx.y, b = blockIdx.z;
    const int px0 = tx * 8, py0 = ty * 8;
    const int tile = ty * 8 + tx;

    // ---- stage x patch (fp32 -> fp16) into ci 0..31 ----
    const float* xt = x + (((size_t)b * 16 + t) * 4096) * 32;
    for (int i = tid; i < 400; i += 256) {
        const int pos = i >> 2, q = i & 3;
        const int row = pos / 10, col = pos - row * 10;
        const int gy = py0 + row - 1, gx = px0 + col - 1;
        half8 hv = {0, 0, 0, 0, 0, 0, 0, 0};
        if ((unsigned)gy < 64u && (unsigned)gx < 64u) {
            const float* s = xt + ((size_t)(gy * 64 + gx)) * 32 + q * 8;
            const float4 v0 = *(const float4*)s;
            const float4 v1 = *(const float4*)(s + 4);
            hv = (half8){(_Float16)v0.x, (_Float16)v0.y, (_Float16)v0.z, (_Float16)v0.w,
                         (_Float16)v1.x, (_Float16)v1.y, (_Float16)v1.z, (_Float16)v1.w};
        }
        *(half8*)&patch[pos * PSTR + q * 8] = hv;
    }
    // ---- stage h patch (fp16) into ci 32..63 ----
    const _Float16* hb = hprev + (size_t)b * 4096 * 32;
    for (int i = tid; i < 400; i += 256) {
        const int pos = i >> 2, q = i & 3;
        const int row = pos / 10, col = pos - row * 10;
        const int gy = py0 + row - 1, gx = px0 + col - 1;
        half8 hv = {0, 0, 0, 0, 0, 0, 0, 0};
        if ((unsigned)gy < 64u && (unsigned)gx < 64u)
            hv = *(const half8*)(hb + ((size_t)(gy * 64 + gx)) * 32 + q * 8);
        *(half8*)&patch[pos * PSTR + 32 + q * 8] = hv;
    }
    __syncthreads();

    const int f = chg * 16 + l15;
    float bi[4];
    #pragma unroll
    for (int nt = 0; nt < 4; ++nt) bi[nt] = bias[nt * 32 + f];

    f32x4 acc[2][4];
    #pragma unroll
    for (int mt = 0; mt < 2; ++mt)
        #pragma unroll
        for (int nt = 0; nt < 4; ++nt)
            acc[mt][nt] = (f32x4){bi[nt], bi[nt], bi[nt], bi[nt]};

    // A: lane m=l15 -> px = mtg*32 + l15 (row-major in 8x8 tile); a1 = +2 rows (+16 px)
    const int pbase = ((mtg * 4 + (l15 >> 3)) * 10 + (l15 & 7)) * PSTR;
    const _Float16* wb = Wc + f * 64;   // row n = nt*32 + f, 64 ci per row

    #pragma unroll
    for (int tap = 0; tap < 9; ++tap) {
        const int ky = tap / 3, kx = tap - ky * 3;
        #pragma unroll
        for (int hk = 0; hk < 2; ++hk) {
            const int ci0 = hk * 32 + quad * 8;
            const half8 a0 = *(const half8*)&patch[pbase + (ky * 10 + kx) * PSTR + ci0];
            const half8 a1 = *(const half8*)&patch[pbase + (ky * 10 + kx + 20) * PSTR + ci0];
            #pragma unroll
            for (int nt = 0; nt < 4; ++nt) {
                const half8 bf = *(const half8*)(wb + tap * 8192 + nt * 2048 + ci0);
                acc[0][nt] = __builtin_amdgcn_mfma_f32_16x16x32_f16(a0, bf, acc[0][nt], 0, 0, 0);
                acc[1][nt] = __builtin_amdgcn_mfma_f32_16x16x32_f16(a1, bf, acc[1][nt], 0, 0, 0);
            }
        }
    }

    // ---- epilogue: lane owns 8 (px,f) pairs with all 4 gates; c lane-contiguous ----
    float* cp = csw + (((size_t)b * 64 + tile) * 256 + tid) * 8;
    f32x4 cold0 = *(const f32x4*)cp;
    f32x4 cold1 = *(const f32x4*)(cp + 4);

    const float inv = gamma_[f] * rsqrtf(mvar[f] + 1e-3f);
    const float bnb = beta_[f] - mmean[f] * inv;

    _Float16* hq = hnext + (size_t)b * 4096 * 32;
    float* oq = out + (((size_t)b * 16 + t) * 4096) * 32;

    f32x4 cn0, cn1;
    #pragma unroll
    for (int mt = 0; mt < 2; ++mt) {
        #pragma unroll
        for (int r = 0; r < 4; ++r) {
            const int px = (mtg * 2 + mt) * 16 + quad * 4 + r;
            const int gy = py0 + (px >> 3), gx = px0 + (px & 7);
            const float gi = acc[mt][0][r];
            const float gf = acc[mt][1][r];
            const float gc = acc[mt][2][r];
            const float go = acc[mt][3][r];
            const float co = mt ? cold1[r] : cold0[r];
            const float cn = hsig(gf) * co + hsig(gi) * fast_tanh(gc);
            const float hv = hsig(go) * fast_tanh(cn);
            if (mt) cn1[r] = cn; else cn0[r] = cn;
            const size_t pix = ((size_t)(gy * 64 + gx)) * 32 + f;
            hq[pix] = (_Float16)hv;
            oq[pix] = hv * inv + bnb;
        }
    }
    *(f32x4*)cp       = cn0;
    *(f32x4*)(cp + 4) = cn1;
}

extern "C" void kernel_launch(void* const* d_in, const int* in_sizes, int n_in,
                              void* d_out, int out_size, void* d_ws, size_t ws_size,
                              hipStream_t stream)
{
    const float* x      = (const float*)d_in[0];
    const float* Wx     = (const float*)d_in[1];
    const float* Wh     = (const float*)d_in[2];
    const float* bias   = (const float*)d_in[3];
    const float* gamma_ = (const float*)d_in[4];
    const float* beta_  = (const float*)d_in[5];
    const float* mmean  = (const float*)d_in[6];
    const float* mvar   = (const float*)d_in[7];
    float* out = (float*)d_out;

    // ws: [h0 fp16 2MB][csw fp32 4MB][h1 fp16 2MB][Wc fp16 147KB]  (~8.4 MB)
    char* wsb = (char*)d_ws;
    _Float16* h0  = (_Float16*)(wsb);
    float*    csw = (float*)(wsb + 2097152);
    _Float16* h1  = (_Float16*)(wsb + 6291456);
    _Float16* Wc  = (_Float16*)(wsb + 8388608);

    hipMemsetAsync(d_ws, 0, 6291456, stream);   // zero h0 + csw
    prep_w<<<dim3(576), dim3(128), 0, stream>>>(Wx, Wh, Wc);

    dim3 gs(8, 8, 8);    // 512 blocks -> 2/CU
    _Float16* hp = h0;
    _Float16* hn = h1;
    for (int t = 0; t < 16; ++t) {
        step<<<gs, 256, 0, stream>>>(x, Wc, bias, gamma_, beta_, mmean, mvar,
                                     hp, hn, csw, out, t);
        _Float16* tmp = hp; hp = hn; hn = tmp;
    }
}